// Round 5
// baseline (370.909 us; speedup 1.0000x reference)
//
#include <hip/hip_runtime.h>

// GCN: N=100000, E=800000, D=128, two GraphConv layers.
// R5: gather fused into the MFMA GEMM — neighbor rows are gathered straight
// into an LDS A-tile (64 rows x 136-ushort pitch), then 4 waves run 16-row
// MFMA tiles. Removes the 25.6MB agg buffer round-trip (100MB/iter of HBM
// traffic) and two kernel launches.
// Atomic floor note (R4): 1.6M device-scope atomics write ~32B sectors
// through to HBM (~51MB observed) -> count_kernel ~80us is structural.

#define NN 100000
#define EE 800000
#define DD 128
#define NB1 98            // ceil(NN / 1024) blocks for scan level 1

typedef __attribute__((ext_vector_type(8))) short short8;
typedef __attribute__((ext_vector_type(4))) float floatx4;

__device__ inline float bf2f(unsigned int u16) {
    union { unsigned int i; float f; } c;
    c.i = u16 << 16;
    return c.f;
}
__device__ inline ushort f2bf(float f) {
    union { float f; unsigned int i; } c;
    c.f = f;
    unsigned int u = c.i;
    return (ushort)((u + 0x7fffu + ((u >> 16) & 1u)) >> 16);  // RNE
}

// ---------------- fused degree count + CSR slot offsets ----------------
__global__ __launch_bounds__(256) void count_kernel(const int* __restrict__ row,
                                                    const int* __restrict__ col,
                                                    int* __restrict__ cnt_out,
                                                    int* __restrict__ cnt_in,
                                                    int* __restrict__ off) {
    int e = blockIdx.x * 256 + threadIdx.x;
    if (e < EE) {
        off[e] = atomicAdd(&cnt_in[col[e]], 1);   // slot within target node
        atomicAdd(&cnt_out[row[e]], 1);
    }
}

__global__ __launch_bounds__(256) void dinv_kernel(const int* __restrict__ cnt_out,
                                                   const int* __restrict__ cnt_in,
                                                   float* __restrict__ dinv_out,
                                                   float* __restrict__ dinv_in) {
    int n = blockIdx.x * 256 + threadIdx.x;
    if (n < NN) {
        dinv_out[n] = rsqrtf((float)max(cnt_out[n], 1));
        dinv_in[n]  = rsqrtf((float)max(cnt_in[n], 1));
    }
}

// ---------------- exclusive scan of cnt_in (3-level) ----------------
__global__ __launch_bounds__(256) void scan1_kernel(const int* __restrict__ cnt,
                                                    int* __restrict__ excl,
                                                    int* __restrict__ bsums) {
    __shared__ int tmp[256];
    const int t = threadIdx.x;
    const int base = blockIdx.x * 1024 + t * 4;
    int a[4];
#pragma unroll
    for (int q = 0; q < 4; ++q) a[q] = (base + q < NN) ? cnt[base + q] : 0;
    int s = a[0] + a[1] + a[2] + a[3];
    tmp[t] = s;
    __syncthreads();
    for (int off = 1; off < 256; off <<= 1) {
        int v = 0;
        if (t >= off) v = tmp[t - off];
        __syncthreads();
        tmp[t] += v;
        __syncthreads();
    }
    int excl_s = tmp[t] - s;
    if (t == 255) bsums[blockIdx.x] = tmp[t];
    int run = excl_s;
#pragma unroll
    for (int q = 0; q < 4; ++q) {
        if (base + q < NN) excl[base + q] = run;
        run += a[q];
    }
}

__global__ __launch_bounds__(256) void scan2_kernel(int* __restrict__ bsums, int nb) {
    __shared__ int tmp[256];
    const int t = threadIdx.x;
    int s = (t < nb) ? bsums[t] : 0;
    tmp[t] = s;
    __syncthreads();
    for (int off = 1; off < 256; off <<= 1) {
        int v = 0;
        if (t >= off) v = tmp[t - off];
        __syncthreads();
        tmp[t] += v;
        __syncthreads();
    }
    if (t < nb) bsums[t] = tmp[t] - s;   // exclusive
}

__global__ __launch_bounds__(256) void scan3_kernel(const int* __restrict__ excl,
                                                    const int* __restrict__ bsums,
                                                    int* __restrict__ row_start) {
    int i = blockIdx.x * 256 + threadIdx.x;
    if (i < NN) row_start[i] = excl[i] + bsums[i >> 10];
}

// ---------------- atomic-free CSR fill ----------------
__global__ __launch_bounds__(256) void fill_kernel(const int* __restrict__ row,
                                                   const int* __restrict__ col,
                                                   const int* __restrict__ row_start,
                                                   const int* __restrict__ off,
                                                   int* __restrict__ srcs) {
    int e = blockIdx.x * 256 + threadIdx.x;
    if (e < EE) srcs[row_start[col[e]] + off[e]] = row[e];
}

// ---------------- xb = bf16(x * dinv_out) ----------------
__global__ __launch_bounds__(256) void prescale_kernel(const float* __restrict__ x,
                                                       const float* __restrict__ dinv_out,
                                                       ushort* __restrict__ xb) {
    int idx = blockIdx.x * 256 + threadIdx.x;   // one float4 per thread
    if (idx >= NN * 32) return;
    int n = idx >> 5;
    float s = dinv_out[n];
    float4 v = ((const float4*)x)[idx];
    ushort4 o;
    o.x = f2bf(v.x * s);
    o.y = f2bf(v.y * s);
    o.z = f2bf(v.z * s);
    o.w = f2bf(v.w * s);
    ((ushort4*)xb)[idx] = o;
}

// ---------------- fused gather + MFMA GEMM + epilogue ----------------
// Per block: 64 node rows. Phase 1: stage W (bf16) + gather neighbor rows
// into LDS A-tile (pitch 136 ushorts: 16B-aligned, 2-way-free LDS writes).
// Phase 2: 4 waves x one 16-row MFMA tile each, all 128 cols.
template <bool L1>
__global__ __launch_bounds__(256) void fused_layer(const ushort* __restrict__ src,
                                                   const int* __restrict__ row_start,
                                                   const int* __restrict__ srcs,
                                                   const float* __restrict__ W,
                                                   const float* __restrict__ bias,
                                                   const float* __restrict__ dinv_in,
                                                   const float* __restrict__ dinv_out,
                                                   const float* __restrict__ x,
                                                   ushort* __restrict__ hs,
                                                   float* __restrict__ out) {
    __shared__ ushort Ws[128 * 136];
    __shared__ ushort At[64 * 136];

    {   // stage W (fp32 -> bf16) into LDS
        int j = threadIdx.x >> 1;
        int k0 = (threadIdx.x & 1) * 64;
        const float4* wp = (const float4*)(W + (size_t)j * DD + k0);
        ushort* dst = Ws + j * 136 + k0;
#pragma unroll
        for (int q = 0; q < 16; ++q) {
            float4 v = wp[q];
            ushort4 o;
            o.x = f2bf(v.x); o.y = f2bf(v.y); o.z = f2bf(v.z); o.w = f2bf(v.w);
            *(ushort4*)(dst + q * 4) = o;
        }
    }

    {   // gather 64 rows into At: 16 groups of 16 lanes, 4 nodes per group
        const int grp  = threadIdx.x >> 4;
        const int lane = threadIdx.x & 15;
        const int m0 = blockIdx.x * 64;
        for (int q = 0; q < 4; ++q) {
            const int node = m0 + q * 16 + grp;
            float a0 = 0.f, a1 = 0.f, a2 = 0.f, a3 = 0.f;
            float a4 = 0.f, a5 = 0.f, a6 = 0.f, a7 = 0.f;
            if (node < NN) {
                int p = row_start[node];
                const int end = (node + 1 < NN) ? row_start[node + 1] : EE;
#define ACCUM(V)                                 \
    do {                                         \
        a0 += bf2f((V).x & 0xffffu);             \
        a1 += bf2f((V).x >> 16);                 \
        a2 += bf2f((V).y & 0xffffu);             \
        a3 += bf2f((V).y >> 16);                 \
        a4 += bf2f((V).z & 0xffffu);             \
        a5 += bf2f((V).z >> 16);                 \
        a6 += bf2f((V).w & 0xffffu);             \
        a7 += bf2f((V).w >> 16);                 \
    } while (0)
                for (; p + 3 < end; p += 4) {
                    int s0 = srcs[p];
                    int s1 = srcs[p + 1];
                    int s2 = srcs[p + 2];
                    int s3 = srcs[p + 3];
                    uint4 v0 = ((const uint4*)(src + (size_t)s0 * DD))[lane];
                    uint4 v1 = ((const uint4*)(src + (size_t)s1 * DD))[lane];
                    uint4 v2 = ((const uint4*)(src + (size_t)s2 * DD))[lane];
                    uint4 v3 = ((const uint4*)(src + (size_t)s3 * DD))[lane];
                    ACCUM(v0); ACCUM(v1); ACCUM(v2); ACCUM(v3);
                }
                for (; p < end; ++p) {
                    int s0 = srcs[p];
                    uint4 v0 = ((const uint4*)(src + (size_t)s0 * DD))[lane];
                    ACCUM(v0);
                }
#undef ACCUM
            }
            uint4 o;
            o.x = (unsigned int)f2bf(a0) | ((unsigned int)f2bf(a1) << 16);
            o.y = (unsigned int)f2bf(a2) | ((unsigned int)f2bf(a3) << 16);
            o.z = (unsigned int)f2bf(a4) | ((unsigned int)f2bf(a5) << 16);
            o.w = (unsigned int)f2bf(a6) | ((unsigned int)f2bf(a7) << 16);
            *(uint4*)(At + (q * 16 + grp) * 136 + lane * 8) = o;
        }
    }
    __syncthreads();

    // ---- MFMA phase: wave w -> rows [w*16, w*16+16) of this block ----
    const int wave = threadIdx.x >> 6;
    const int lane = threadIdx.x & 63;
    const int mi = lane & 15;
    const int quad = lane >> 4;
    const int m0 = blockIdx.x * 64 + wave * 16;

    floatx4 acc[8];
#pragma unroll
    for (int t = 0; t < 8; ++t) acc[t] = (floatx4){0.f, 0.f, 0.f, 0.f};

    const ushort* ap = At + (wave * 16 + mi) * 136 + quad * 8;
#pragma unroll
    for (int s = 0; s < 4; ++s) {
        short8 a = *(const short8*)(ap + s * 32);
#pragma unroll
        for (int t = 0; t < 8; ++t) {
            short8 b = *(const short8*)(Ws + (t * 16 + mi) * 136 + s * 32 + quad * 8);
            acc[t] = __builtin_amdgcn_mfma_f32_16x16x32_bf16(a, b, acc[t], 0, 0, 0);
        }
    }

    // C/D layout: col = lane&15, row = quad*4 + reg
    float dv[4], dov[4];
#pragma unroll
    for (int i = 0; i < 4; ++i) {
        int r = m0 + quad * 4 + i;
        int rc = r < NN ? r : (NN - 1);
        dv[i] = dinv_in[rc];
        if (L1) dov[i] = dinv_out[rc];
    }
#pragma unroll
    for (int t = 0; t < 8; ++t) {
        int c = t * 16 + mi;
        float bv = bias[c];
#pragma unroll
        for (int i = 0; i < 4; ++i) {
            int r = m0 + quad * 4 + i;
            if (r < NN) {
                float o = (acc[t][i] + bv) * dv[i];
                if (L1) {
                    o += x[(size_t)r * DD + c];
                    o = fmaxf(o, 0.f);
                    hs[(size_t)r * DD + c] = f2bf(o * dov[i]);
                } else {
                    out[(size_t)r * DD + c] = o;
                }
            }
        }
    }
}

extern "C" void kernel_launch(void* const* d_in, const int* in_sizes, int n_in,
                              void* d_out, int out_size, void* d_ws, size_t ws_size,
                              hipStream_t stream) {
    const float* x  = (const float*)d_in[0];
    const int*   ei = (const int*)d_in[1];
    const float* W1 = (const float*)d_in[2];
    const float* b1 = (const float*)d_in[3];
    const float* W2 = (const float*)d_in[4];
    const float* b2 = (const float*)d_in[5];
    float* out = (float*)d_out;

    const int* row = ei;        // edge_index[0] (source)
    const int* col = ei + EE;   // edge_index[1] (target)

    // workspace layout. off[] aliases hs[]: off is dead after fill_kernel,
    // hs is first written by fused_layer<true> (after fill). xb and hs must
    // NOT alias (fused L1 reads xb while writing hs).
    ushort* xb      = (ushort*)d_ws;                 // N*DD bf16 (25.6 MB)
    ushort* hs      = xb + (size_t)NN * DD;          // N*DD bf16 (25.6 MB)
    int*    off     = (int*)hs;                      // E ints (aliased, dead early)
    float* dinv_out = (float*)(hs + (size_t)NN * DD);
    float* dinv_in  = dinv_out + NN;
    int*   cnt      = (int*)(dinv_in + NN);          // 2*N (cnt_out, cnt_in)
    int*   excl     = cnt + 2 * NN;                  // N
    int*   row_st   = excl + NN;                     // N
    int*   srcs     = row_st + NN;                   // E
    int*   bsums    = srcs + EE;                     // 256

    // ---- degrees + CSR build (reused by both layers) ----
    hipMemsetAsync(cnt, 0, 2 * NN * sizeof(int), stream);
    count_kernel<<<(EE + 255) / 256, 256, 0, stream>>>(row, col, cnt, cnt + NN, off);
    dinv_kernel<<<(NN + 255) / 256, 256, 0, stream>>>(cnt, cnt + NN, dinv_out, dinv_in);
    scan1_kernel<<<NB1, 256, 0, stream>>>(cnt + NN, excl, bsums);
    scan2_kernel<<<1, 256, 0, stream>>>(bsums, NB1);
    scan3_kernel<<<(NN + 255) / 256, 256, 0, stream>>>(excl, bsums, row_st);
    fill_kernel<<<(EE + 255) / 256, 256, 0, stream>>>(row, col, row_st, off, srcs);

    // ---- layer 1: gather(xb) + GEMM(W1) -> hs (prescaled bf16) ----
    prescale_kernel<<<(NN * 32 + 255) / 256, 256, 0, stream>>>(x, dinv_out, xb);
    fused_layer<true><<<(NN + 63) / 64, 256, 0, stream>>>(xb, row_st, srcs, W1, b1,
                                                          dinv_in, dinv_out, x, hs, nullptr);

    // ---- layer 2: gather(hs) + GEMM(W2) -> out (fp32) ----
    fused_layer<false><<<(NN + 63) / 64, 256, 0, stream>>>(hs, row_st, srcs, W2, b2,
                                                           dinv_in, nullptr, nullptr, nullptr, out);
}

// Round 6
// 316.714 us; speedup vs baseline: 1.1711x; 1.1711x over previous
//
#include <hip/hip_runtime.h>

// GCN: N=100000, E=800000, D=128, two GraphConv layers.
// R6: revert R5 fusion (occupancy collapse). R4 structure + launch-count diet:
//  - countcast: degree atomics co-run with the unscaled x->bf16 cast
//    (cast has no degree dependency; gather scales by dinv_out[src] per edge)
//  - scanB: scan2+scan3+dinv folded into one 98-block kernel (redundant
//    98-element LDS scan per block), writes row_start[NN]=EE sentinel
//  - hb aliases xb (dead after gather1); off aliases agg (dead after fill)
// Atomic floor (R4): 1.6M device-scope atomics ~ 51MB HBM sector writes ~80us.

#define NN 100000
#define EE 800000
#define DD 128
#define NB1 98            // ceil(NN / 1024) scan blocks
#define CB  3125          // EE / 256 count blocks
#define XB  12500         // NN*32 / 256 cast blocks (float4 granularity)
#define NTILE (NN / 16)   // 6250 MFMA row-tiles

typedef __attribute__((ext_vector_type(8))) short short8;
typedef __attribute__((ext_vector_type(4))) float floatx4;

__device__ inline float bf2f(unsigned int u16) {
    union { unsigned int i; float f; } c;
    c.i = u16 << 16;
    return c.f;
}
__device__ inline ushort f2bf(float f) {
    union { float f; unsigned int i; } c;
    c.f = f;
    unsigned int u = c.i;
    return (ushort)((u + 0x7fffu + ((u >> 16) & 1u)) >> 16);  // RNE
}

// ---------------- fused: degree count + CSR slot offsets | x -> bf16 cast ----------------
__global__ __launch_bounds__(256) void countcast_kernel(const int* __restrict__ row,
                                                        const int* __restrict__ col,
                                                        int* __restrict__ cnt_out,
                                                        int* __restrict__ cnt_in,
                                                        int* __restrict__ off,
                                                        const float* __restrict__ x,
                                                        ushort* __restrict__ xb) {
    const int b = blockIdx.x;
    if (b < CB) {
        int e = b * 256 + threadIdx.x;
        off[e] = atomicAdd(&cnt_in[col[e]], 1);   // slot within target node
        atomicAdd(&cnt_out[row[e]], 1);
    } else {
        int idx = (b - CB) * 256 + threadIdx.x;   // one float4 per thread
        float4 v = ((const float4*)x)[idx];
        ushort4 o;
        o.x = f2bf(v.x); o.y = f2bf(v.y); o.z = f2bf(v.z); o.w = f2bf(v.w);
        ((ushort4*)xb)[idx] = o;
    }
}

// ---------------- scan level 1: per-1024-chunk exclusive scan + block sums ----------------
__global__ __launch_bounds__(256) void scan1_kernel(const int* __restrict__ cnt,
                                                    int* __restrict__ excl,
                                                    int* __restrict__ bsums) {
    __shared__ int tmp[256];
    const int t = threadIdx.x;
    const int base = blockIdx.x * 1024 + t * 4;
    int a[4];
#pragma unroll
    for (int q = 0; q < 4; ++q) a[q] = (base + q < NN) ? cnt[base + q] : 0;
    int s = a[0] + a[1] + a[2] + a[3];
    tmp[t] = s;
    __syncthreads();
    for (int off = 1; off < 256; off <<= 1) {
        int v = 0;
        if (t >= off) v = tmp[t - off];
        __syncthreads();
        tmp[t] += v;
        __syncthreads();
    }
    int excl_s = tmp[t] - s;
    if (t == 255) bsums[blockIdx.x] = tmp[t];
    int run = excl_s;
#pragma unroll
    for (int q = 0; q < 4; ++q) {
        if (base + q < NN) excl[base + q] = run;
        run += a[q];
    }
}

// ---------------- scan level 2 + apply + dinv, one kernel ----------------
// Each of the 98 blocks redundantly scans the 98 block sums in LDS, then
// applies its prefix and computes dinv_in/dinv_out for its 1024 nodes.
__global__ __launch_bounds__(256) void scanB_kernel(const int* __restrict__ excl,
                                                    const int* __restrict__ bsums,
                                                    const int* __restrict__ cnt_out,
                                                    const int* __restrict__ cnt_in,
                                                    int* __restrict__ row_start,
                                                    float* __restrict__ dinv_out,
                                                    float* __restrict__ dinv_in) {
    __shared__ int tmp[128];
    const int t = threadIdx.x;
    if (t < 128) tmp[t] = (t < NB1) ? bsums[t] : 0;
    __syncthreads();
    for (int off = 1; off < 128; off <<= 1) {
        int v = 0;
        if (t < 128 && t >= off) v = tmp[t - off];
        __syncthreads();
        if (t < 128) tmp[t] += v;
        __syncthreads();
    }
    const int base = (blockIdx.x == 0) ? 0 : tmp[blockIdx.x - 1];  // exclusive prefix
    const int i0 = blockIdx.x * 1024 + t * 4;
#pragma unroll
    for (int q = 0; q < 4; ++q) {
        int i = i0 + q;
        if (i < NN) {
            row_start[i] = excl[i] + base;
            dinv_in[i]  = rsqrtf((float)max(cnt_in[i], 1));
            dinv_out[i] = rsqrtf((float)max(cnt_out[i], 1));
        }
    }
    if (blockIdx.x == 0 && t == 0) row_start[NN] = EE;
}

// ---------------- atomic-free CSR fill ----------------
__global__ __launch_bounds__(256) void fill_kernel(const int* __restrict__ row,
                                                   const int* __restrict__ col,
                                                   const int* __restrict__ row_start,
                                                   const int* __restrict__ off,
                                                   int* __restrict__ srcs) {
    int e = blockIdx.x * 256 + threadIdx.x;
    if (e < EE) srcs[row_start[col[e]] + off[e]] = row[e];
}

// ---------------- gather: 16 lanes/node, uint4/lane, 4-edge unroll ----------------
// Per-edge scale by dinv_out[src] (broadcast 4B L2 read, replaces prescale pass).
__global__ __launch_bounds__(256) void gather_kernel(const ushort* __restrict__ src,
                                                     const int* __restrict__ row_start,
                                                     const int* __restrict__ srcs,
                                                     const float* __restrict__ dinv_out,
                                                     ushort* __restrict__ agg) {
    const int node = blockIdx.x * 16 + (threadIdx.x >> 4);
    const int lane = threadIdx.x & 15;
    if (node >= NN) return;
    int p = row_start[node];
    const int end = row_start[node + 1];
    float a0 = 0.f, a1 = 0.f, a2 = 0.f, a3 = 0.f;
    float a4 = 0.f, a5 = 0.f, a6 = 0.f, a7 = 0.f;

#define ACCUM(V, C)                                  \
    do {                                             \
        a0 += bf2f((V).x & 0xffffu) * (C);           \
        a1 += bf2f((V).x >> 16) * (C);               \
        a2 += bf2f((V).y & 0xffffu) * (C);           \
        a3 += bf2f((V).y >> 16) * (C);               \
        a4 += bf2f((V).z & 0xffffu) * (C);           \
        a5 += bf2f((V).z >> 16) * (C);               \
        a6 += bf2f((V).w & 0xffffu) * (C);           \
        a7 += bf2f((V).w >> 16) * (C);               \
    } while (0)

    for (; p + 3 < end; p += 4) {
        int s0 = srcs[p];
        int s1 = srcs[p + 1];
        int s2 = srcs[p + 2];
        int s3 = srcs[p + 3];
        float c0 = dinv_out[s0];
        float c1 = dinv_out[s1];
        float c2 = dinv_out[s2];
        float c3 = dinv_out[s3];
        uint4 v0 = ((const uint4*)(src + (size_t)s0 * DD))[lane];
        uint4 v1 = ((const uint4*)(src + (size_t)s1 * DD))[lane];
        uint4 v2 = ((const uint4*)(src + (size_t)s2 * DD))[lane];
        uint4 v3 = ((const uint4*)(src + (size_t)s3 * DD))[lane];
        ACCUM(v0, c0); ACCUM(v1, c1); ACCUM(v2, c2); ACCUM(v3, c3);
    }
    for (; p < end; ++p) {
        int s0 = srcs[p];
        float c0 = dinv_out[s0];
        uint4 v0 = ((const uint4*)(src + (size_t)s0 * DD))[lane];
        ACCUM(v0, c0);
    }
#undef ACCUM

    uint4 o;
    o.x = (unsigned int)f2bf(a0) | ((unsigned int)f2bf(a1) << 16);
    o.y = (unsigned int)f2bf(a2) | ((unsigned int)f2bf(a3) << 16);
    o.z = (unsigned int)f2bf(a4) | ((unsigned int)f2bf(a5) << 16);
    o.w = (unsigned int)f2bf(a6) | ((unsigned int)f2bf(a7) << 16);
    ((uint4*)(agg + (size_t)node * DD))[lane] = o;
}

// ---------------- MFMA bf16 GEMM + epilogue ----------------
// C[m, j] = sum_k agg[m,k] * W[j,k]. 4 waves/block, one 16-row tile each.
// W staged fp32->bf16 into LDS (pitch 136). A-frags straight from global.
// L1 epilogue: hb = bf16(relu((acc+b)*dinv_in + x)) (unscaled; gather2 scales).
template <bool L1>
__global__ __launch_bounds__(256) void gemm_ep(const ushort* __restrict__ agg,
                                               const float* __restrict__ W,
                                               const float* __restrict__ bias,
                                               const float* __restrict__ dinv_in,
                                               const float* __restrict__ x,
                                               ushort* __restrict__ hb,
                                               float* __restrict__ out) {
    __shared__ ushort Ws[128 * 136];
    {   // stage W (fp32 -> bf16) into LDS
        int j = threadIdx.x >> 1;
        int k0 = (threadIdx.x & 1) * 64;
        const float4* wp = (const float4*)(W + (size_t)j * DD + k0);
        ushort* dst = Ws + j * 136 + k0;
#pragma unroll
        for (int q = 0; q < 16; ++q) {
            float4 v = wp[q];
            ushort4 o;
            o.x = f2bf(v.x); o.y = f2bf(v.y); o.z = f2bf(v.z); o.w = f2bf(v.w);
            *(ushort4*)(dst + q * 4) = o;
        }
    }
    __syncthreads();

    const int wave = threadIdx.x >> 6;
    const int lane = threadIdx.x & 63;
    const int tile = blockIdx.x * 4 + wave;
    if (tile >= NTILE) return;
    const int mi = lane & 15;
    const int quad = lane >> 4;
    const int m0 = tile * 16;

    floatx4 acc[8];
#pragma unroll
    for (int t = 0; t < 8; ++t) acc[t] = (floatx4){0.f, 0.f, 0.f, 0.f};

    const ushort* ap = agg + (size_t)(m0 + mi) * DD + quad * 8;
#pragma unroll
    for (int s = 0; s < 4; ++s) {
        short8 a = *(const short8*)(ap + s * 32);
#pragma unroll
        for (int t = 0; t < 8; ++t) {
            short8 b = *(const short8*)(Ws + (t * 16 + mi) * 136 + s * 32 + quad * 8);
            acc[t] = __builtin_amdgcn_mfma_f32_16x16x32_bf16(a, b, acc[t], 0, 0, 0);
        }
    }

    // C/D layout: col = lane&15, row = quad*4 + reg
    float dv[4];
#pragma unroll
    for (int i = 0; i < 4; ++i) dv[i] = dinv_in[m0 + quad * 4 + i];
#pragma unroll
    for (int t = 0; t < 8; ++t) {
        int c = t * 16 + mi;
        float bv = bias[c];
#pragma unroll
        for (int i = 0; i < 4; ++i) {
            int r = m0 + quad * 4 + i;
            float o = (acc[t][i] + bv) * dv[i];
            if (L1) {
                o += x[(size_t)r * DD + c];
                o = fmaxf(o, 0.f);
                hb[(size_t)r * DD + c] = f2bf(o);
            } else {
                out[(size_t)r * DD + c] = o;
            }
        }
    }
}

extern "C" void kernel_launch(void* const* d_in, const int* in_sizes, int n_in,
                              void* d_out, int out_size, void* d_ws, size_t ws_size,
                              hipStream_t stream) {
    const float* x  = (const float*)d_in[0];
    const int*   ei = (const int*)d_in[1];
    const float* W1 = (const float*)d_in[2];
    const float* b1 = (const float*)d_in[3];
    const float* W2 = (const float*)d_in[4];
    const float* b2 = (const float*)d_in[5];
    float* out = (float*)d_out;

    const int* row = ei;        // edge_index[0] (source)
    const int* col = ei + EE;   // edge_index[1] (target)

    // workspace. Aliases: off over agg (off dead after fill, agg written by
    // gather1 which runs after fill); hb over xb (xb dead after gather1,
    // hb first written by gemm1 which runs after gather1).
    ushort* agg     = (ushort*)d_ws;                 // N*DD bf16 (25.6 MB)
    ushort* xb      = agg + (size_t)NN * DD;         // N*DD bf16 (25.6 MB)
    ushort* hb      = xb;                            // aliased
    int*    off     = (int*)agg;                     // E ints (aliased)
    float* dinv_out = (float*)(xb + (size_t)NN * DD);
    float* dinv_in  = dinv_out + NN;
    int*   cnt      = (int*)(dinv_in + NN);          // 2*N (cnt_out, cnt_in)
    int*   excl     = cnt + 2 * NN;                  // N
    int*   row_st   = excl + NN;                     // N+1
    int*   srcs     = row_st + NN + 1;               // E
    int*   bsums    = srcs + EE;                     // 128

    // ---- degrees + cast (overlapped) + CSR build ----
    hipMemsetAsync(cnt, 0, 2 * NN * sizeof(int), stream);
    countcast_kernel<<<CB + XB, 256, 0, stream>>>(row, col, cnt, cnt + NN, off, x, xb);
    scan1_kernel<<<NB1, 256, 0, stream>>>(cnt + NN, excl, bsums);
    scanB_kernel<<<NB1, 256, 0, stream>>>(excl, bsums, cnt, cnt + NN, row_st,
                                          dinv_out, dinv_in);
    fill_kernel<<<(EE + 255) / 256, 256, 0, stream>>>(row, col, row_st, off, srcs);

    // ---- layer 1 ----
    gather_kernel<<<(NN + 15) / 16, 256, 0, stream>>>(xb, row_st, srcs, dinv_out, agg);
    gemm_ep<true><<<(NTILE + 3) / 4, 256, 0, stream>>>(agg, W1, b1, dinv_in, x, hb, nullptr);

    // ---- layer 2 ----
    gather_kernel<<<(NN + 15) / 16, 256, 0, stream>>>(hb, row_st, srcs, dinv_out, agg);
    gemm_ep<false><<<(NTILE + 3) / 4, 256, 0, stream>>>(agg, W2, b2, dinv_in, nullptr, nullptr, out);
}